// Round 18
// baseline (67.176 us; speedup 1.0000x reference)
//
#include <hip/hip_runtime.h>
#include <hip/hip_bf16.h>
#include <stdint.h>

typedef unsigned long long u64;
typedef float f32x2 __attribute__((ext_vector_type(2)));
typedef float f32x4 __attribute__((ext_vector_type(4)));

#define N 8192
#define K 30
#define NWAVE 2                 // waves per block (128 threads); 1 row per wave
#define NSLOT 11
#define CAP 704                 // 11 slots * 64 lanes
#define FLUSH_AT 192            // influx <= 512/iter -> cnt <= 704 after check

// ws layout: gx[8192] @0 | gy @32768 | gz @65536 | gw @98304 | gid @131072 | ctr @163840
// gx..gw validity-COMPACTED: [0,nValid) valid, tail w=+inf. gid[p] = original index.
// NOTE: depth-2 prefetch may over-read each array by <=5 KB into the next ws
// region (gy/gz/gw/gid) — allocated workspace, values never consumed. Safe.

static __device__ __forceinline__ f32x2 pk_mul(f32x2 a, f32x2 b) {
  f32x2 d; asm("v_pk_mul_f32 %0, %1, %2" : "=v"(d) : "v"(a), "v"(b)); return d;
}
static __device__ __forceinline__ f32x2 pk_add(f32x2 a, f32x2 b) {
  f32x2 d; asm("v_pk_add_f32 %0, %1, %2" : "=v"(d) : "v"(a), "v"(b)); return d;
}
static __device__ __forceinline__ f32x2 pk_fma(f32x2 a, f32x2 b, f32x2 c) {
  f32x2 d; asm("v_pk_fma_f32 %0, %1, %2, %3" : "=v"(d) : "v"(a), "v"(b), "v"(c)); return d;
}
static __device__ __forceinline__ f32x2 clamp0(f32x2 a) {   // exact, = jnp.maximum(d2,0)
  f32x2 d; d.x = fmaxf(a.x, 0.0f); d.y = fmaxf(a.y, 0.0f); return d;
}

__global__ void zero_kernel(int* __restrict__ ctr) {
  if (threadIdx.x < 2) ctr[threadIdx.x] = 0;
}

// ---------------- prep: centroid + sq + validity, COMPACTED SoA ----------------
__global__ __launch_bounds__(256) void prep_kernel(const float* __restrict__ X,
                                                   const int* __restrict__ C,
                                                   float* __restrict__ gx,
                                                   float* __restrict__ gy,
                                                   float* __restrict__ gz,
                                                   float* __restrict__ gw,
                                                   int* __restrict__ gid,
                                                   int* __restrict__ ctr) {
  int i = blockIdx.x * 256 + threadIdx.x;
  if (i >= N) return;
  const float4* xp = (const float4*)(X + (size_t)i * 12);
  float4 f0 = xp[0], f1 = xp[1], f2 = xp[2];
  float mx = __fmul_rn(__fadd_rn(__fadd_rn(__fadd_rn(f0.x, f0.w), f1.z), f2.y), 0.25f);
  float my = __fmul_rn(__fadd_rn(__fadd_rn(__fadd_rn(f0.y, f1.x), f1.w), f2.z), 0.25f);
  float mz = __fmul_rn(__fadd_rn(__fadd_rn(__fadd_rn(f0.z, f1.y), f2.x), f2.w), 0.25f);
  float sq = __fadd_rn(__fadd_rn(__fmul_rn(mx, mx), __fmul_rn(my, my)), __fmul_rn(mz, mz));
  bool valid = (C[i] > 0);
  int p;
  if (valid) p = atomicAdd(&ctr[0], 1);
  else       p = N - 1 - atomicAdd(&ctr[1], 1);
  gx[p] = mx; gy[p] = my; gz[p] = mz;
  gw[p] = valid ? sq : __builtin_inff();
  gid[p] = i;
}

// ---------------- bitonic helpers (validated; final phase only) ----------------
static __device__ __forceinline__ u64 sort64(u64 v, int lane) {
#pragma unroll
  for (int kk = 2; kk <= 64; kk <<= 1) {
#pragma unroll
    for (int j = kk >> 1; j > 0; j >>= 1) {
      u64 o = __shfl_xor(v, j);
      bool lower = (lane & j) == 0;
      bool asc = (lane & kk) == 0;
      u64 mn = v < o ? v : o;
      u64 mx = v < o ? o : v;
      v = (lower == asc) ? mn : mx;
    }
  }
  return v;
}
static __device__ __forceinline__ u64 merge64(u64 L, u64 v, int lane) {
  u64 vr = __shfl(v, 63 - lane);
  u64 m = L < vr ? L : vr;
#pragma unroll
  for (int j = 32; j > 0; j >>= 1) {
    u64 o = __shfl_xor(m, j);
    bool lower = (lane & j) == 0;
    u64 mn = m < o ? m : o;
    u64 mx = m < o ? o : m;
    m = lower ? mn : mx;
  }
  return m;
}

static __device__ __forceinline__ unsigned mbcnt64(u64 mask) {
  return __builtin_amdgcn_mbcnt_hi((unsigned)(mask >> 32),
         __builtin_amdgcn_mbcnt_lo((unsigned)mask, 0u));
}

// -------- radix flush: theta via 16-round bit search (ballots only), purge --------
__device__ __forceinline__ void radix_flush(float& th, unsigned& cnt,
                                            unsigned* bd, unsigned* bj, int lane) {
  unsigned h[NSLOT], j[NSLOT];
#pragma unroll
  for (int s = 0; s < NSLOT; ++s) {
    bool in = (unsigned)(lane + 64 * s) < cnt;
    h[s] = in ? bd[lane + 64 * s] : 0xFFFFFFFFu;
    j[s] = in ? bj[lane + 64 * s] : 0u;
  }
  unsigned piv = 0;
#pragma unroll
  for (int b = 15; b >= 0; --b) {
    unsigned cand = piv + (0x10000u << b);
    int c = 0;
#pragma unroll
    for (int s = 0; s < NSLOT; ++s) c += __popcll(__ballot(h[s] < cand));
    if (c < K) piv = cand;           // invariant: count(< piv) < K
  }
  if (piv < 0xFFFF0000u)
    th = fminf(th, __uint_as_float(piv + 0x10000u));

  const unsigned thb = __float_as_uint(th);
  unsigned total = 0;
#pragma unroll
  for (int s = 0; s < NSLOT; ++s) {
    u64 mk = __ballot(h[s] < thb);
    if (mk) {
      unsigned pos = total + mbcnt64(mk);
      if (h[s] < thb) { bd[pos] = h[s]; bj[pos] = j[s]; }
      total += (unsigned)__popcll(mk);
    }
  }
  cnt = total;
}

// -------- final: tighten+purge, gather ORIGINAL indices, one exact bitonic pass ---
__device__ __forceinline__ u64 finalize_row(float& th, unsigned& cnt,
                                            unsigned* bd, unsigned* bj,
                                            const int* __restrict__ gid, int lane) {
  radix_flush(th, cnt, bd, bj, lane);
  u64 L = ~0ull;
  for (unsigned base = 0; base < cnt; base += 64) {
    u64 v = ~0ull;
    if (base + (unsigned)lane < cnt) {
      float d2c = __uint_as_float(bd[base + lane]);
      float D = sqrtf(__fadd_rn(d2c, 1e-6f));            // exact ref formula
      unsigned jo = (unsigned)gid[bj[base + lane]];
      v = ((u64)__float_as_uint(D) << 32) | jo;
    }
    v = sort64(v, lane);
    L = merge64(L, v, lane);
  }
  return L;
}

// flattened accept: mbcnt position, split b32 writes, no 64-bit pack
#define PROC_NB(MASK, PRED, DV, JJ)                                           \
  { unsigned pos = cnt + mbcnt64(MASK);                                       \
    if (PRED) { bd[pos] = __float_as_uint(DV); bj[pos] = (JJ); }              \
    cnt += (unsigned)__popcll(MASK); }

__device__ __forceinline__ void write_row(int r, bool act, u64 L, int lane,
                                          __hip_bfloat16* __restrict__ out) {
  if (lane >= K) return;
  const int o = r * K + lane;
  if (act) {
    out[o] = __float2bfloat16((float)(unsigned)(L & 0xFFFFFFFFull));
    out[N * K + o] = __float2bfloat16(__uint_as_float((unsigned)(L >> 32)));
    out[2 * N * K + o] = __float2bfloat16(1.0f);
  } else {
    out[o] = __float2bfloat16((float)lane);
    ((unsigned short*)out)[N * K + o] = 0x7F7Fu;   // finite bf16-max vs expected inf
    out[2 * N * K + o] = __float2bfloat16(0.0f);
  }
}

// -- main: 1 row/wave, compacted table, 512 cands/iter (2 f32x4 groups), depth-2 ---
// -- even/odd stages, single-ballot early-out, radix flush, exact finalize.        --
__global__ __launch_bounds__(128) void knn_kernel(const float* __restrict__ gx,
                                                  const float* __restrict__ gy,
                                                  const float* __restrict__ gz,
                                                  const float* __restrict__ gw,
                                                  const int* __restrict__ gid,
                                                  const int* __restrict__ ctr,
                                                  __hip_bfloat16* __restrict__ out) {
  __shared__ unsigned bufD[NWAVE][CAP];
  __shared__ unsigned bufJ[NWAVE][CAP];

  const int lane = threadIdx.x & 63;
  const int w = threadIdx.x >> 6;
  const int nValid = ctr[0];
  const int pos = blockIdx.x * NWAVE + w;
  const int rout = gid[pos];
  const bool act = pos < nValid;

  if (!act) {                // inactive wave: defaults + leave (no barriers)
    write_row(rout, false, 0, lane, out);
    return;
  }

  const float qx = gx[pos], qy = gy[pos], qz = gz[pos], qw = gw[pos];
  const f32x2 qx2 = {qx, qx}, qy2 = {qy, qy}, qz2 = {qz, qz}, qw2 = {qw, qw};
  const f32x2 neg1 = {-1.0f, -1.0f};

  float th = __builtin_inff();
  unsigned cnt = 0;
  unsigned* bd = &bufD[w][0];
  unsigned* bj = &bufJ[w][0];

  const f32x4* bx4 = (const f32x4*)gx;
  const f32x4* by4 = (const f32x4*)gy;
  const f32x4* bz4 = (const f32x4*)gz;
  const f32x4* bw4 = (const f32x4*)gw;

  const int niter = (nValid + 511) >> 9;   // 512 candidates (128 f32x4) per iter

  // two register stages (even/odd), each = 2 groups of f32x4 per array
  f32x4 A0X, A0Y, A0Z, A0W, A1X, A1Y, A1Z, A1W;
  f32x4 B0X, B0Y, B0Z, B0W, B1X, B1Y, B1Z, B1W;
#define LOADS(P, B4)                                                           \
  P##0X = bx4[(B4) + lane]; P##0Y = by4[(B4) + lane];                          \
  P##0Z = bz4[(B4) + lane]; P##0W = bw4[(B4) + lane];                          \
  P##1X = bx4[(B4) + 64 + lane]; P##1Y = by4[(B4) + 64 + lane];                \
  P##1Z = bz4[(B4) + 64 + lane]; P##1W = bw4[(B4) + 64 + lane];

  LOADS(A, 0)
  LOADS(B, 128)

  // distance for one f32x4 group -> two f32x2 results
#define D2G(GX, GY, GZ, GW, DLO, DHI)                                          \
  {                                                                            \
    f32x2 xlo = {GX.x, GX.y}, xhi = {GX.z, GX.w};                              \
    f32x2 ylo = {GY.x, GY.y}, yhi = {GY.z, GY.w};                              \
    f32x2 zlo = {GZ.x, GZ.y}, zhi = {GZ.z, GZ.w};                              \
    f32x2 wlo = {GW.x, GW.y}, whi = {GW.z, GW.w};                              \
    f32x2 dtl = pk_add(pk_add(pk_mul(qx2, xlo), pk_mul(qy2, ylo)),             \
                       pk_mul(qz2, zlo));                                      \
    DLO = clamp0(pk_fma(pk_add(dtl, dtl), neg1, pk_add(qw2, wlo)));            \
    f32x2 dth = pk_add(pk_add(pk_mul(qx2, xhi), pk_mul(qy2, yhi)),             \
                       pk_mul(qz2, zhi));                                      \
    DHI = clamp0(pk_fma(pk_add(dth, dth), neg1, pk_add(qw2, whi)));            \
  }

#define ITERX(P, IT, PRIME)                                                    \
  {                                                                            \
    const int bb4 = (IT) * 128;                                                \
    f32x2 d0lo, d0hi, d1lo, d1hi;                                              \
    D2G(P##0X, P##0Y, P##0Z, P##0W, d0lo, d0hi)                                \
    D2G(P##1X, P##1Y, P##1Z, P##1W, d1lo, d1hi)                                \
    LOADS(P, bb4 + 256)   /* depth-2 prefetch; over-read lands in ws (safe) */ \
    float mn = fminf(fminf(fminf(d0lo.x, d0lo.y), fminf(d0hi.x, d0hi.y)),      \
                     fminf(fminf(d1lo.x, d1lo.y), fminf(d1hi.x, d1hi.y)));     \
    if (PRIME && nValid >= 512) {                                              \
      float l = mn;                                                            \
      _Pragma("unroll")                                                        \
      for (int d = 32; d; d >>= 1) l = fmaxf(l, __shfl_xor(l, d));             \
      th = l;   /* >=64 candidates <= th  =>  th >= true 30th (exact) */       \
    }                                                                          \
    u64 anym = __ballot(mn <= th);                                             \
    if (anym) {                                                                \
      bool p0 = d0lo.x <= th, p1 = d0lo.y <= th;                               \
      bool p2 = d0hi.x <= th, p3 = d0hi.y <= th;                               \
      bool p4 = d1lo.x <= th, p5 = d1lo.y <= th;                               \
      bool p6 = d1hi.x <= th, p7 = d1hi.y <= th;                               \
      u64 m0 = __ballot(p0), m1 = __ballot(p1);                                \
      u64 m2 = __ballot(p2), m3 = __ballot(p3);                                \
      u64 m4 = __ballot(p4), m5 = __ballot(p5);                                \
      u64 m6 = __ballot(p6), m7 = __ballot(p7);                                \
      const unsigned j0 = (unsigned)(4 * (bb4 + lane));                        \
      const unsigned j1 = j0 + 256;                                            \
      PROC_NB(m0, p0, d0lo.x, j0)                                              \
      PROC_NB(m1, p1, d0lo.y, j0 + 1)                                          \
      PROC_NB(m2, p2, d0hi.x, j0 + 2)                                          \
      PROC_NB(m3, p3, d0hi.y, j0 + 3)                                          \
      PROC_NB(m4, p4, d1lo.x, j1)                                              \
      PROC_NB(m5, p5, d1lo.y, j1 + 1)                                          \
      PROC_NB(m6, p6, d1hi.x, j1 + 2)                                          \
      PROC_NB(m7, p7, d1hi.y, j1 + 3)                                          \
      if (cnt > FLUSH_AT) radix_flush(th, cnt, bd, bj, lane);                  \
    }                                                                          \
  }

  ITERX(A, 0, true)                        // peeled: theta-prime
  if (niter > 1) ITERX(B, 1, false)
  int it = 2;
#pragma unroll 1
  for (; it + 1 < niter; it += 2) {
    ITERX(A, it, false)
    ITERX(B, it + 1, false)
  }
  if (it < niter) ITERX(A, it, false)

  u64 L = finalize_row(th, cnt, bd, bj, gid, lane);
  write_row(rout, true, L, lane, out);
}

extern "C" void kernel_launch(void* const* d_in, const int* in_sizes, int n_in,
                              void* d_out, int out_size, void* d_ws, size_t ws_size,
                              hipStream_t stream) {
  const float* X = (const float*)d_in[0];
  const int* C = (const int*)d_in[1];
  float* gx = (float*)d_ws;
  float* gy = (float*)((char*)d_ws + 32768);
  float* gz = (float*)((char*)d_ws + 65536);
  float* gw = (float*)((char*)d_ws + 98304);
  int* gid = (int*)((char*)d_ws + 131072);
  int* ctr = (int*)((char*)d_ws + 163840);
  __hip_bfloat16* out = (__hip_bfloat16*)d_out;

  zero_kernel<<<1, 64, 0, stream>>>(ctr);
  prep_kernel<<<N / 256, 256, 0, stream>>>(X, C, gx, gy, gz, gw, gid, ctr);
  knn_kernel<<<N / NWAVE, 128, 0, stream>>>(gx, gy, gz, gw, gid, ctr, out);
}

// Round 19
// 56.208 us; speedup vs baseline: 1.1951x; 1.1951x over previous
//
#include <hip/hip_runtime.h>
#include <hip/hip_bf16.h>
#include <stdint.h>

typedef unsigned long long u64;
typedef float f32x2 __attribute__((ext_vector_type(2)));
typedef float f32x4 __attribute__((ext_vector_type(4)));

#define N 8192
#define K 30
#define NWAVE 4                 // waves per block (256 threads); 1 row per wave
#define NSLOT 9
#define CAP 576                 // 9 slots * 64 lanes
#define FLUSH_AT 320            // influx <= 256/iter -> cnt <= 576 after check

// ws layout: gx[8192] @0 | gy @32768 | gz @65536 | gw @98304 | gid @131072 | ctr @163840
// gx..gw validity-COMPACTED: [0,nValid) valid, tail w=+inf. gid[p] = original index.
// NOTE: knn prefetch may over-read gw by <2.1 KB into the gid region — allocated
// workspace, values never consumed (stage beyond niter is dead). Safe by design.

static __device__ __forceinline__ f32x2 pk_mul(f32x2 a, f32x2 b) {
  f32x2 d; asm("v_pk_mul_f32 %0, %1, %2" : "=v"(d) : "v"(a), "v"(b)); return d;
}
static __device__ __forceinline__ f32x2 pk_add(f32x2 a, f32x2 b) {
  f32x2 d; asm("v_pk_add_f32 %0, %1, %2" : "=v"(d) : "v"(a), "v"(b)); return d;
}
static __device__ __forceinline__ f32x2 pk_fma(f32x2 a, f32x2 b, f32x2 c) {
  f32x2 d; asm("v_pk_fma_f32 %0, %1, %2, %3" : "=v"(d) : "v"(a), "v"(b), "v"(c)); return d;
}
static __device__ __forceinline__ f32x2 clamp0(f32x2 a) {   // exact, = jnp.maximum(d2,0)
  f32x2 d; d.x = fmaxf(a.x, 0.0f); d.y = fmaxf(a.y, 0.0f); return d;
}

__global__ void zero_kernel(int* __restrict__ ctr) {
  if (threadIdx.x < 2) ctr[threadIdx.x] = 0;
}

// ---------------- prep: centroid + sq + validity, COMPACTED SoA ----------------
__global__ __launch_bounds__(256) void prep_kernel(const float* __restrict__ X,
                                                   const int* __restrict__ C,
                                                   float* __restrict__ gx,
                                                   float* __restrict__ gy,
                                                   float* __restrict__ gz,
                                                   float* __restrict__ gw,
                                                   int* __restrict__ gid,
                                                   int* __restrict__ ctr) {
  int i = blockIdx.x * 256 + threadIdx.x;
  if (i >= N) return;
  const float4* xp = (const float4*)(X + (size_t)i * 12);
  float4 f0 = xp[0], f1 = xp[1], f2 = xp[2];
  float mx = __fmul_rn(__fadd_rn(__fadd_rn(__fadd_rn(f0.x, f0.w), f1.z), f2.y), 0.25f);
  float my = __fmul_rn(__fadd_rn(__fadd_rn(__fadd_rn(f0.y, f1.x), f1.w), f2.z), 0.25f);
  float mz = __fmul_rn(__fadd_rn(__fadd_rn(__fadd_rn(f0.z, f1.y), f2.x), f2.w), 0.25f);
  float sq = __fadd_rn(__fadd_rn(__fmul_rn(mx, mx), __fmul_rn(my, my)), __fmul_rn(mz, mz));
  bool valid = (C[i] > 0);
  int p;
  if (valid) p = atomicAdd(&ctr[0], 1);
  else       p = N - 1 - atomicAdd(&ctr[1], 1);
  gx[p] = mx; gy[p] = my; gz[p] = mz;
  gw[p] = valid ? sq : __builtin_inff();
  gid[p] = i;
}

// ---------------- bitonic helpers (validated; final phase only) ----------------
static __device__ __forceinline__ u64 sort64(u64 v, int lane) {
#pragma unroll
  for (int kk = 2; kk <= 64; kk <<= 1) {
#pragma unroll
    for (int j = kk >> 1; j > 0; j >>= 1) {
      u64 o = __shfl_xor(v, j);
      bool lower = (lane & j) == 0;
      bool asc = (lane & kk) == 0;
      u64 mn = v < o ? v : o;
      u64 mx = v < o ? o : v;
      v = (lower == asc) ? mn : mx;
    }
  }
  return v;
}
static __device__ __forceinline__ u64 merge64(u64 L, u64 v, int lane) {
  u64 vr = __shfl(v, 63 - lane);
  u64 m = L < vr ? L : vr;
#pragma unroll
  for (int j = 32; j > 0; j >>= 1) {
    u64 o = __shfl_xor(m, j);
    bool lower = (lane & j) == 0;
    u64 mn = m < o ? m : o;
    u64 mx = m < o ? o : m;
    m = lower ? mn : mx;
  }
  return m;
}

static __device__ __forceinline__ unsigned mbcnt64(u64 mask) {
  return __builtin_amdgcn_mbcnt_hi((unsigned)(mask >> 32),
         __builtin_amdgcn_mbcnt_lo((unsigned)mask, 0u));
}

// -------- radix flush: theta via 16-round bit search (ballots only), purge --------
// Split buffers: bd = clamped d2 bits (non-neg: uint order = value order), bj = idx.
__device__ __forceinline__ void radix_flush(float& th, unsigned& cnt,
                                            unsigned* bd, unsigned* bj, int lane) {
  unsigned h[NSLOT], j[NSLOT];
#pragma unroll
  for (int s = 0; s < NSLOT; ++s) {
    bool in = (unsigned)(lane + 64 * s) < cnt;
    h[s] = in ? bd[lane + 64 * s] : 0xFFFFFFFFu;
    j[s] = in ? bj[lane + 64 * s] : 0u;
  }
  unsigned piv = 0;
#pragma unroll
  for (int b = 15; b >= 0; --b) {
    unsigned cand = piv + (0x10000u << b);
    int c = 0;
#pragma unroll
    for (int s = 0; s < NSLOT; ++s) c += __popcll(__ballot(h[s] < cand));
    if (c < K) piv = cand;           // invariant: count(< piv) < K
  }
  if (piv < 0xFFFF0000u)
    th = fminf(th, __uint_as_float(piv + 0x10000u));

  const unsigned thb = __float_as_uint(th);
  unsigned total = 0;
#pragma unroll
  for (int s = 0; s < NSLOT; ++s) {
    u64 mk = __ballot(h[s] < thb);
    if (mk) {
      unsigned pos = total + mbcnt64(mk);
      if (h[s] < thb) { bd[pos] = h[s]; bj[pos] = j[s]; }
      total += (unsigned)__popcll(mk);
    }
  }
  cnt = total;
}

// -------- final: tighten+purge, gather ORIGINAL indices, one exact bitonic pass ---
__device__ __forceinline__ u64 finalize_row(float& th, unsigned& cnt,
                                            unsigned* bd, unsigned* bj,
                                            const int* __restrict__ gid, int lane) {
  radix_flush(th, cnt, bd, bj, lane);
  u64 L = ~0ull;
  for (unsigned base = 0; base < cnt; base += 64) {
    u64 v = ~0ull;
    if (base + (unsigned)lane < cnt) {
      float d2c = __uint_as_float(bd[base + lane]);
      float D = sqrtf(__fadd_rn(d2c, 1e-6f));            // exact ref formula
      unsigned jo = (unsigned)gid[bj[base + lane]];
      v = ((u64)__float_as_uint(D) << 32) | jo;
    }
    v = sort64(v, lane);
    L = merge64(L, v, lane);
  }
  return L;
}

// flattened accept: mbcnt position, split b32 writes, no 64-bit pack
#define PROC_NB(MASK, PRED, DV, JJ)                                           \
  { unsigned pos = cnt + mbcnt64(MASK);                                       \
    if (PRED) { bd[pos] = __float_as_uint(DV); bj[pos] = (JJ); }              \
    cnt += (unsigned)__popcll(MASK); }

__device__ __forceinline__ void write_row(int r, bool act, u64 L, int lane,
                                          __hip_bfloat16* __restrict__ out) {
  if (lane >= K) return;
  const int o = r * K + lane;
  if (act) {
    out[o] = __float2bfloat16((float)(unsigned)(L & 0xFFFFFFFFull));
    out[N * K + o] = __float2bfloat16(__uint_as_float((unsigned)(L >> 32)));
    out[2 * N * K + o] = __float2bfloat16(1.0f);
  } else {
    out[o] = __float2bfloat16((float)lane);
    ((unsigned short*)out)[N * K + o] = 0x7F7Fu;   // finite bf16-max vs expected inf
    out[2 * N * K + o] = __float2bfloat16(0.0f);
  }
}

// -- main: 1 row/wave, compacted table, dwordx4 SoA loads, depth-2 stages, ---------
// -- single-ballot early-out, lean accept path, radix flush, exact finalize.       --
__global__ __launch_bounds__(256) void knn_kernel(const float* __restrict__ gx,
                                                  const float* __restrict__ gy,
                                                  const float* __restrict__ gz,
                                                  const float* __restrict__ gw,
                                                  const int* __restrict__ gid,
                                                  const int* __restrict__ ctr,
                                                  __hip_bfloat16* __restrict__ out) {
  __shared__ unsigned bufD[NWAVE][CAP];
  __shared__ unsigned bufJ[NWAVE][CAP];

  const int lane = threadIdx.x & 63;
  const int w = threadIdx.x >> 6;
  const int nValid = ctr[0];
  const int pos = blockIdx.x * NWAVE + w;
  const int rout = gid[pos];
  const bool act = pos < nValid;

  if (!act) {                // inactive wave: defaults + leave (no barriers)
    write_row(rout, false, 0, lane, out);
    return;
  }

  const float qx = gx[pos], qy = gy[pos], qz = gz[pos], qw = gw[pos];
  const f32x2 qx2 = {qx, qx}, qy2 = {qy, qy}, qz2 = {qz, qz}, qw2 = {qw, qw};
  const f32x2 neg1 = {-1.0f, -1.0f};

  float th = __builtin_inff();
  unsigned cnt = 0;
  unsigned* bd = &bufD[w][0];
  unsigned* bj = &bufJ[w][0];

  const f32x4* bx4 = (const f32x4*)gx;
  const f32x4* by4 = (const f32x4*)gy;
  const f32x4* bz4 = (const f32x4*)gz;
  const f32x4* bw4 = (const f32x4*)gw;

  const int niter = (nValid + 255) >> 8;   // 256 candidates (64 f32x4) per iter

  // two register stages (even/odd), depth-2 prefetch via reload-after-consume
  f32x4 AX, AY, AZ, AW, BX, BY, BZ, BW;
#define LOADS(P, B4)                                                           \
  P##X = bx4[(B4) + lane]; P##Y = by4[(B4) + lane];                            \
  P##Z = bz4[(B4) + lane]; P##W = bw4[(B4) + lane];

  LOADS(A, 0)
  LOADS(B, 64)

#define ITERX(P, IT, PRIME)                                                    \
  {                                                                            \
    const int bb4 = (IT) * 64;                                                 \
    f32x2 xlo = {P##X.x, P##X.y}, xhi = {P##X.z, P##X.w};                      \
    f32x2 ylo = {P##Y.x, P##Y.y}, yhi = {P##Y.z, P##Y.w};                      \
    f32x2 zlo = {P##Z.x, P##Z.y}, zhi = {P##Z.z, P##Z.w};                      \
    f32x2 wlo = {P##W.x, P##W.y}, whi = {P##W.z, P##W.w};                      \
    f32x2 dtl = pk_add(pk_add(pk_mul(qx2, xlo), pk_mul(qy2, ylo)),             \
                       pk_mul(qz2, zlo));                                      \
    f32x2 dlo = clamp0(pk_fma(pk_add(dtl, dtl), neg1, pk_add(qw2, wlo)));      \
    f32x2 dth = pk_add(pk_add(pk_mul(qx2, xhi), pk_mul(qy2, yhi)),             \
                       pk_mul(qz2, zhi));                                      \
    f32x2 dhi = clamp0(pk_fma(pk_add(dth, dth), neg1, pk_add(qw2, whi)));      \
    LOADS(P, bb4 + 128)   /* depth-2 prefetch; over-read lands in ws (safe) */ \
    float mn = fminf(fminf(dlo.x, dlo.y), fminf(dhi.x, dhi.y));                \
    if (PRIME && nValid >= 256) {                                              \
      float l = mn;                                                            \
      _Pragma("unroll")                                                        \
      for (int d = 32; d; d >>= 1) l = fmaxf(l, __shfl_xor(l, d));             \
      th = l;   /* >=64 candidates <= th  =>  th >= true 30th (exact) */       \
    }                                                                          \
    u64 anym = __ballot(mn <= th);                                             \
    if (anym) {                                                                \
      bool p0 = dlo.x <= th, p1 = dlo.y <= th, p2 = dhi.x <= th, p3 = dhi.y <= th; \
      u64 m0 = __ballot(p0), m1 = __ballot(p1);                                \
      u64 m2 = __ballot(p2), m3 = __ballot(p3);                                \
      const unsigned j0 = (unsigned)(4 * (bb4 + lane));                        \
      PROC_NB(m0, p0, dlo.x, j0)                                               \
      PROC_NB(m1, p1, dlo.y, j0 + 1)                                           \
      PROC_NB(m2, p2, dhi.x, j0 + 2)                                           \
      PROC_NB(m3, p3, dhi.y, j0 + 3)                                           \
      if (cnt > FLUSH_AT) radix_flush(th, cnt, bd, bj, lane);                  \
    }                                                                          \
  }

  ITERX(A, 0, true)                        // peeled: theta-prime
  if (niter > 1) ITERX(B, 1, false)
  int it = 2;
#pragma unroll 1
  for (; it + 1 < niter; it += 2) {
    ITERX(A, it, false)
    ITERX(B, it + 1, false)
  }
  if (it < niter) ITERX(A, it, false)

  u64 L = finalize_row(th, cnt, bd, bj, gid, lane);
  write_row(rout, true, L, lane, out);
}

extern "C" void kernel_launch(void* const* d_in, const int* in_sizes, int n_in,
                              void* d_out, int out_size, void* d_ws, size_t ws_size,
                              hipStream_t stream) {
  const float* X = (const float*)d_in[0];
  const int* C = (const int*)d_in[1];
  float* gx = (float*)d_ws;
  float* gy = (float*)((char*)d_ws + 32768);
  float* gz = (float*)((char*)d_ws + 65536);
  float* gw = (float*)((char*)d_ws + 98304);
  int* gid = (int*)((char*)d_ws + 131072);
  int* ctr = (int*)((char*)d_ws + 163840);
  __hip_bfloat16* out = (__hip_bfloat16*)d_out;

  zero_kernel<<<1, 64, 0, stream>>>(ctr);
  prep_kernel<<<N / 256, 256, 0, stream>>>(X, C, gx, gy, gz, gw, gid, ctr);
  knn_kernel<<<N / NWAVE, 256, 0, stream>>>(gx, gy, gz, gw, gid, ctr, out);
}